// Round 1
// baseline (493.338 us; speedup 1.0000x reference)
//
#include <hip/hip_runtime.h>

#define NI 32
#define CI 128
#define HI 112
#define WI 112
#define OC 256
#define HO 110
#define WO 110

typedef float f32x4 __attribute__((ext_vector_type(4)));
typedef short s16x8 __attribute__((ext_vector_type(8)));

__device__ __forceinline__ ushort f2bf(float f) {
  union { float f; unsigned int u; } x; x.f = f;
  unsigned int r = x.u + 0x7FFFu + ((x.u >> 16) & 1u);
  return (ushort)(r >> 16);
}

// weight [oc][c][kh][kw] fp32 -> wp [kk=kh*3+kw][oc][c] bf16
__global__ __launch_bounds__(256) void pack_w_kernel(const float* __restrict__ w,
                                                     ushort* __restrict__ wp) {
  int i = blockIdx.x * 256 + threadIdx.x;  // 9*256*128 = 294912
  int c = i & 127;
  int rest = i >> 7;
  int oc = rest & 255;
  int kk = rest >> 8;  // 0..8
  int kh = kk / 3, kw = kk - kh * 3;
  wp[i] = f2bf(w[((oc * CI + c) * 3 + kh) * 3 + kw]);
}

// x [n][c][h][w] fp32 -> xn [n][h][w][c] bf16 (per-block: one (n,h) row, LDS transpose)
__global__ __launch_bounds__(256) void to_nhwc_kernel(const float* __restrict__ x,
                                                      ushort* __restrict__ xn) {
  __shared__ ushort lds[WI * CI];  // 14336 ushorts = 28 KB
  int b = blockIdx.x;              // n*112 + h
  int n = b / HI;
  int h = b - n * HI;
  const float* xr = x + ((size_t)n * CI * HI) * WI + (size_t)h * WI;  // + c*12544 + w
  int t = threadIdx.x;
  for (int i = t; i < WI * CI; i += 256) {
    int w = i >> 7, c = i & 127;                   // consecutive t -> consecutive c
    lds[i] = f2bf(xr[(size_t)c * (HI * WI) + w]);  // lds[w*128 + c]
  }
  __syncthreads();
  uint4* dst = (uint4*)(xn + (size_t)b * (WI * CI));
  const uint4* src = (const uint4*)lds;
  for (int i = t; i < (WI * CI) / 8; i += 256) dst[i] = src[i];
}

// Implicit GEMM: block = (n, 2 output rows) x 256 oc.
// A = weights [oc][c] from global (L2-resident), B = input patches from swizzled LDS.
// D: rows = oc (M), cols = ow (N)  => coalesced stores.
__global__ __launch_bounds__(512, 2) void conv_mfma_kernel(const ushort* __restrict__ xn,
                                                           const ushort* __restrict__ wp,
                                                           const float* __restrict__ bias,
                                                           float* __restrict__ out) {
  // 4 staged input rows [4][112][128] bf16 + 2 pad pixel-rows = 450*128 ushorts = 115200 B
  __shared__ ushort lds[450 * 128];
  const int bid = blockIdx.x;
  const int n = bid / 55;
  const int rp = bid - n * 55;
  const int oh0 = rp * 2;
  const int t = threadIdx.x;
  const int lane = t & 63;
  const int wid = t >> 6;
  const int lane15 = lane & 15;
  const int laneh = lane >> 4;

  // ---- stage 4 rows (oh0..oh0+3), XOR-swizzled: elem_idx ^= ((pix&7)<<3) ----
  const ushort* gsrc = xn + ((size_t)n * HI + oh0) * (WI * CI);
  #pragma unroll
  for (int i = 0; i < 14; ++i) {
    int de = (i * 512 + t) * 8;  // element offset, 8 bf16 = 16 B per thread-iter
    int pix = de >> 7;
    int sw = de ^ ((pix & 7) << 3);
    *(s16x8*)(lds + sw) = *(const s16x8*)(gsrc + de);
  }
  __syncthreads();

  const int ocq = wid & 3;   // oc quarter
  const int ph = wid >> 2;   // which of the 2 output rows
  const int oc0 = ocq * 64;

  f32x4 acc[4][7] = {};  // [mf: oc 16-frag][nf: ow 16-frag]

  #pragma unroll
  for (int kh = 0; kh < 3; ++kh) {
    #pragma unroll
    for (int kw = 0; kw < 3; ++kw) {
      const int kk = kh * 3 + kw;
      const ushort* wbase = wp + ((size_t)(kk * OC + oc0 + lane15) * CI) + laneh * 8;
      const int prow = (ph + kh) * WI + kw;
      #pragma unroll
      for (int cc = 0; cc < 4; ++cc) {  // K chunks of 32 channels
        s16x8 a[4];
        s16x8 bfr[7];
        #pragma unroll
        for (int mf = 0; mf < 4; ++mf)
          a[mf] = *(const s16x8*)(wbase + mf * 16 * CI + cc * 32);
        #pragma unroll
        for (int nf = 0; nf < 7; ++nf) {
          int pix = prow + nf * 16 + lane15;
          int idx = (pix << 7) + (((cc * 32) + laneh * 8) ^ ((pix & 7) << 3));
          bfr[nf] = *(const s16x8*)(lds + idx);
        }
        #pragma unroll
        for (int mf = 0; mf < 4; ++mf)
          #pragma unroll
          for (int nf = 0; nf < 7; ++nf)
            acc[mf][nf] =
                __builtin_amdgcn_mfma_f32_16x16x32_bf16(a[mf], bfr[nf], acc[mf][nf], 0, 0, 0);
      }
    }
  }

  // ---- epilogue: bias + store (D: col=lane&15 -> ow, row=(lane>>4)*4+r -> oc) ----
  const int oh = oh0 + ph;
  float bv[4][4];
  #pragma unroll
  for (int mf = 0; mf < 4; ++mf)
    #pragma unroll
    for (int r = 0; r < 4; ++r)
      bv[mf][r] = bias[oc0 + mf * 16 + laneh * 4 + r];

  float* outb = out + ((size_t)n * OC * HO + oh) * WO;
  #pragma unroll
  for (int mf = 0; mf < 4; ++mf) {
    #pragma unroll
    for (int r = 0; r < 4; ++r) {
      const int oc = oc0 + mf * 16 + laneh * 4 + r;
      float* op = outb + (size_t)oc * (HO * WO);
      #pragma unroll
      for (int nf = 0; nf < 7; ++nf) {
        int ow = nf * 16 + lane15;
        if (ow < WO) op[ow] = acc[mf][nf][r] + bv[mf][r];
      }
    }
  }
}

// Correctness fallback if ws is too small for the packed bf16 buffers.
__global__ __launch_bounds__(256) void conv_naive_kernel(const float* __restrict__ x,
                                                         const float* __restrict__ w,
                                                         const float* __restrict__ bias,
                                                         float* __restrict__ out) {
  long i = (long)blockIdx.x * 256 + threadIdx.x;
  const long total = (long)NI * OC * HO * WO;
  if (i >= total) return;
  int ow = (int)(i % WO);
  long r1 = i / WO;
  int oh = (int)(r1 % HO);
  long r2 = r1 / HO;
  int oc = (int)(r2 % OC);
  int n = (int)(r2 / OC);
  float s = bias[oc];
  const float* xb = x + ((size_t)n * CI * HI) * WI;
  const float* wb = w + (size_t)oc * CI * 9;
  for (int c = 0; c < CI; ++c)
    for (int kh = 0; kh < 3; ++kh)
      for (int kw = 0; kw < 3; ++kw)
        s += xb[((size_t)c * HI + oh + kh) * WI + ow + kw] * wb[(c * 3 + kh) * 3 + kw];
  out[i] = s;
}

extern "C" void kernel_launch(void* const* d_in, const int* in_sizes, int n_in,
                              void* d_out, int out_size, void* d_ws, size_t ws_size,
                              hipStream_t stream) {
  const float* x = (const float*)d_in[0];
  const float* w = (const float*)d_in[1];
  const float* bias = (const float*)d_in[2];
  float* out = (float*)d_out;

  const size_t xn_elems = (size_t)NI * HI * WI * CI;  // 51,380,224
  const size_t wp_elems = (size_t)9 * OC * CI;        // 294,912
  const size_t need = (xn_elems + wp_elems) * sizeof(ushort);

  if (ws_size >= need) {
    ushort* xnw = (ushort*)d_ws;
    ushort* wpw = xnw + xn_elems;
    hipLaunchKernelGGL(pack_w_kernel, dim3((unsigned)(wp_elems / 256)), dim3(256), 0, stream,
                       w, wpw);
    hipLaunchKernelGGL(to_nhwc_kernel, dim3(NI * HI), dim3(256), 0, stream, x, xnw);
    hipLaunchKernelGGL(conv_mfma_kernel, dim3(NI * 55), dim3(512), 0, stream, xnw, wpw, bias,
                       out);
  } else {
    long total = (long)NI * OC * HO * WO;
    hipLaunchKernelGGL(conv_naive_kernel, dim3((unsigned)((total + 255) / 256)), dim3(256), 0,
                       stream, x, w, bias, out);
  }
}